// Round 5
// baseline (977.081 us; speedup 1.0000x reference)
//
#include <hip/hip_runtime.h>

#define NUM_USERS 100000
#define NUM_ITEMS 50000
#define N_NODES   150000
#define DIM       64
#define NNZ_E     2400000
#define NQ        4096

// ---------------------------------------------------------------------------
// 1) init: x0 = concat(user_emb, item_emb); zero the per-row counters
// ---------------------------------------------------------------------------
__global__ void init_kernel(const float* __restrict__ user_emb,
                            const float* __restrict__ item_emb,
                            float* __restrict__ x0, int* __restrict__ cnt) {
    const int total = N_NODES * DIM;
    const int stride = gridDim.x * blockDim.x;
    for (int i = blockIdx.x * blockDim.x + threadIdx.x; i < total; i += stride) {
        float v = (i < NUM_USERS * DIM) ? user_emb[i] : item_emb[i - NUM_USERS * DIM];
        x0[i] = v;
    }
    for (int i = blockIdx.x * blockDim.x + threadIdx.x; i < N_NODES; i += stride)
        cnt[i] = 0;
}

// ---------------------------------------------------------------------------
// 2) histogram of edge_rows
// ---------------------------------------------------------------------------
__global__ void hist_kernel(const int* __restrict__ rows, int* __restrict__ cnt) {
    const int stride = gridDim.x * blockDim.x;
    for (int e = blockIdx.x * blockDim.x + threadIdx.x; e < NNZ_E; e += stride)
        atomicAdd(&cnt[rows[e]], 1);
}

// ---------------------------------------------------------------------------
// 3) exclusive scan (single block, 1024 threads, serial chunks).
//    Writes row_ptr[0..N]; rewrites cnt[i] in place as the scatter cursor.
// ---------------------------------------------------------------------------
__global__ __launch_bounds__(1024) void scan_kernel(int* __restrict__ cnt,
                                                    int* __restrict__ row_ptr) {
    __shared__ int sums[1024];
    __shared__ int offs[1025];
    const int t = threadIdx.x;
    const int chunk = (N_NODES + 1023) / 1024;           // 147
    const int begin = t * chunk;
    const int end   = min(begin + chunk, N_NODES);
    int s = 0;
    for (int i = begin; i < end; ++i) s += cnt[i];
    sums[t] = s;
    __syncthreads();
    if (t == 0) {
        int run = 0;
        for (int i = 0; i < 1024; ++i) { offs[i] = run; run += sums[i]; }
        offs[1024] = run;
    }
    __syncthreads();
    int run = offs[t];
    for (int i = begin; i < end; ++i) {
        int c = cnt[i];
        row_ptr[i] = run;
        cnt[i]     = run;   // becomes the scatter cursor
        run += c;
    }
    if (t == 1023) row_ptr[N_NODES] = offs[1024];
}

// ---------------------------------------------------------------------------
// 4) scatter edges into CSR order (cursor = cnt)
// ---------------------------------------------------------------------------
__global__ void scatter_kernel(const int* __restrict__ rows, const int* __restrict__ cols,
                               const float* __restrict__ vals, int* __restrict__ cursor,
                               int* __restrict__ csr_col, float* __restrict__ csr_val) {
    const int stride = gridDim.x * blockDim.x;
    for (int e = blockIdx.x * blockDim.x + threadIdx.x; e < NNZ_E; e += stride) {
        int r = rows[e];
        int p = atomicAdd(&cursor[r], 1);
        csr_col[p] = cols[e];
        csr_val[p] = vals[e];
    }
}

// ---------------------------------------------------------------------------
// 5) SpMM pull, wide variant: one wave per row.
//    Lane layout: g = lane>>4 is the edge slot (4 concurrent edges),
//    d4 = (lane&15)*4 is the float4 dim base (16 lanes cover DIM=64).
//    2 edge-slots unrolled -> 8 edges in flight per iteration.
//    Epilogue: shfl_xor(16), shfl_xor(32) folds edge slots; lanes 0-15 store.
// ---------------------------------------------------------------------------
__global__ __launch_bounds__(256) void spmm_kernel(const int* __restrict__ row_ptr,
                            const int* __restrict__ csr_col, const float* __restrict__ csr_val,
                            const float* __restrict__ x_in, float* __restrict__ x_out) {
    const int lane = threadIdx.x & 63;
    const int row  = blockIdx.x * 4 + (threadIdx.x >> 6);
    if (row >= N_NODES) return;
    const int s  = row_ptr[row];
    const int e  = row_ptr[row + 1];
    const int g  = lane >> 4;         // edge slot 0..3
    const int d4 = (lane & 15) * 4;   // dim base

    float sx = 0.f, sy = 0.f, sz = 0.f, sw = 0.f;
    for (int i = s; i < e; i += 8) {
        const int idx0 = i + g;
        const int idx1 = i + g + 4;
        if (idx0 < e) {
            const int   c = csr_col[idx0];
            const float v = csr_val[idx0];
            const float4 xv = *reinterpret_cast<const float4*>(&x_in[(size_t)c * DIM + d4]);
            sx += v * xv.x; sy += v * xv.y; sz += v * xv.z; sw += v * xv.w;
        }
        if (idx1 < e) {
            const int   c = csr_col[idx1];
            const float v = csr_val[idx1];
            const float4 xv = *reinterpret_cast<const float4*>(&x_in[(size_t)c * DIM + d4]);
            sx += v * xv.x; sy += v * xv.y; sz += v * xv.z; sw += v * xv.w;
        }
    }
    // fold the 4 edge slots (lanes differing in bits 4,5 hold same dims)
    sx += __shfl_xor(sx, 16, 64); sy += __shfl_xor(sy, 16, 64);
    sz += __shfl_xor(sz, 16, 64); sw += __shfl_xor(sw, 16, 64);
    sx += __shfl_xor(sx, 32, 64); sy += __shfl_xor(sy, 32, 64);
    sz += __shfl_xor(sz, 32, 64); sw += __shfl_xor(sw, 32, 64);

    if (lane < 16) {
        float4 r; r.x = sx; r.y = sy; r.z = sz; r.w = sw;
        *reinterpret_cast<float4*>(&x_out[(size_t)row * DIM + d4]) = r;
    }
}

// ---------------------------------------------------------------------------
// 6) gather-accumulate queried rows into d_out: out += 0.25 * x[node]
//    (FIRST=true initializes out instead of adding)
// ---------------------------------------------------------------------------
template <bool FIRST>
__global__ void gacc_kernel(const float* __restrict__ x, const int* __restrict__ user_ids,
                            const int* __restrict__ item_ids, float* __restrict__ out) {
    const int tid = blockIdx.x * blockDim.x + threadIdx.x;
    if (tid >= 2 * NQ * DIM) return;
    const int i = tid >> 6;
    const int d = tid & 63;
    int node;
    if (i < NQ) node = user_ids[i];
    else        node = NUM_USERS + item_ids[i - NQ];
    float v = 0.25f * x[(size_t)node * DIM + d];
    if (FIRST) out[tid] = v;
    else       out[tid] += v;
}

// ---------------------------------------------------------------------------
extern "C" void kernel_launch(void* const* d_in, const int* in_sizes, int n_in,
                              void* d_out, int out_size, void* d_ws, size_t ws_size,
                              hipStream_t stream) {
    const float* user_emb  = (const float*)d_in[0];
    const float* item_emb  = (const float*)d_in[1];
    const float* edge_vals = (const float*)d_in[2];
    const int*   edge_rows = (const int*)d_in[3];
    const int*   edge_cols = (const int*)d_in[4];
    const int*   user_ids  = (const int*)d_in[5];
    const int*   item_ids  = (const int*)d_in[6];
    float* out = (float*)d_out;

    // workspace carve-up (256B aligned); total ~97.3 MB
    char* ws = (char*)d_ws;
    size_t off = 0;
    auto carve = [&](size_t bytes) {
        char* p = ws + off; off += (bytes + 255) & ~(size_t)255; return p;
    };
    float* x0      = (float*)carve((size_t)N_NODES * DIM * sizeof(float));   // 38.4 MB
    float* x1      = (float*)carve((size_t)N_NODES * DIM * sizeof(float));   // 38.4 MB
    int*   cnt     = (int*)  carve((size_t)N_NODES * sizeof(int));           // 0.6 MB
    int*   row_ptr = (int*)  carve((size_t)(N_NODES + 1) * sizeof(int));     // 0.6 MB
    int*   csr_col = (int*)  carve((size_t)NNZ_E * sizeof(int));             // 9.6 MB
    float* csr_val = (float*)carve((size_t)NNZ_E * sizeof(float));           // 9.6 MB
    (void)in_sizes; (void)n_in; (void)out_size;

    // Defensive: if the workspace is smaller than the carve, launching would
    // write out of bounds and can kill the container (indistinguishable from
    // infra failure). Bail cleanly instead -> shows up as a validation error.
    if (ws_size < off) return;

    const int gth_grid = (2 * NQ * DIM + 255) / 256;

    // 1) init x0 (+ zero counters)
    hipLaunchKernelGGL(init_kernel, dim3(2048), dim3(256), 0, stream,
                       user_emb, item_emb, x0, cnt);
    // out = 0.25 * x0[queried]
    hipLaunchKernelGGL((gacc_kernel<true>), dim3(gth_grid), dim3(256), 0, stream,
                       x0, user_ids, item_ids, out);
    // 2) histogram
    hipLaunchKernelGGL(hist_kernel, dim3(2048), dim3(256), 0, stream, edge_rows, cnt);
    // 3) scan (cnt -> row_ptr, cnt becomes cursor)
    hipLaunchKernelGGL(scan_kernel, dim3(1), dim3(1024), 0, stream, cnt, row_ptr);
    // 4) scatter into CSR
    hipLaunchKernelGGL(scatter_kernel, dim3(2048), dim3(256), 0, stream,
                       edge_rows, edge_cols, edge_vals, cnt, csr_col, csr_val);
    // 5) three SpMM hops (ping-pong x0/x1), each followed by gather-accumulate
    const int spmm_grid = (N_NODES + 3) / 4;   // 4 waves (rows) per 256-thread block
    float* xin = x0; float* xout = x1;
    for (int h = 0; h < 3; ++h) {
        hipLaunchKernelGGL(spmm_kernel, dim3(spmm_grid), dim3(256), 0, stream,
                           row_ptr, csr_col, csr_val, xin, xout);
        hipLaunchKernelGGL((gacc_kernel<false>), dim3(gth_grid), dim3(256), 0, stream,
                           xout, user_ids, item_ids, out);
        float* t = xin; xin = xout; xout = t;
    }
}

// Round 6
// 657.625 us; speedup vs baseline: 1.4858x; 1.4858x over previous
//
#include <hip/hip_runtime.h>

#define NUM_USERS 100000
#define NUM_ITEMS 50000
#define N_NODES   150000
#define DIM       64
#define NNZ_E     2400000
#define NQ        4096

#define SCAN_CHUNK  1024                                     // elements per block
#define SCAN_BLOCKS ((N_NODES + SCAN_CHUNK - 1) / SCAN_CHUNK) // 147
static_assert(SCAN_BLOCKS <= 256, "pass2 assumes <=256 block sums");

// ---------------------------------------------------------------------------
// 1) init: x0 = concat(user_emb, item_emb); zero the per-row counters
// ---------------------------------------------------------------------------
__global__ void init_kernel(const float* __restrict__ user_emb,
                            const float* __restrict__ item_emb,
                            float* __restrict__ x0, int* __restrict__ cnt) {
    const int total = N_NODES * DIM;
    const int stride = gridDim.x * blockDim.x;
    for (int i = blockIdx.x * blockDim.x + threadIdx.x; i < total; i += stride) {
        float v = (i < NUM_USERS * DIM) ? user_emb[i] : item_emb[i - NUM_USERS * DIM];
        x0[i] = v;
    }
    for (int i = blockIdx.x * blockDim.x + threadIdx.x; i < N_NODES; i += stride)
        cnt[i] = 0;
}

// ---------------------------------------------------------------------------
// 2) histogram of edge_rows
// ---------------------------------------------------------------------------
__global__ void hist_kernel(const int* __restrict__ rows, int* __restrict__ cnt) {
    const int stride = gridDim.x * blockDim.x;
    for (int e = blockIdx.x * blockDim.x + threadIdx.x; e < NNZ_E; e += stride)
        atomicAdd(&cnt[rows[e]], 1);
}

// ---------------------------------------------------------------------------
// 3a) scan pass 1: per-block reduction of cnt -> bsum[b]
//     block b covers [b*1024, b*1024+1024), thread t loads 4 consecutive ints
// ---------------------------------------------------------------------------
__global__ __launch_bounds__(256) void scan_reduce_kernel(const int* __restrict__ cnt,
                                                          int* __restrict__ bsum) {
    const int t = threadIdx.x;
    const int base = blockIdx.x * SCAN_CHUNK + t * 4;
    int s = 0;
#pragma unroll
    for (int j = 0; j < 4; ++j) {
        const int i = base + j;
        if (i < N_NODES) s += cnt[i];
    }
    for (int off = 32; off; off >>= 1) s += __shfl_down(s, off, 64);
    __shared__ int ws[4];
    if ((t & 63) == 0) ws[t >> 6] = s;
    __syncthreads();
    if (t == 0) bsum[blockIdx.x] = ws[0] + ws[1] + ws[2] + ws[3];
}

// ---------------------------------------------------------------------------
// 3b) scan pass 2: single block, exclusive scan of the 147 block sums
// ---------------------------------------------------------------------------
__global__ __launch_bounds__(256) void scan_offsets_kernel(const int* __restrict__ bsum,
                                                           int* __restrict__ boff) {
    const int t = threadIdx.x;
    const int v = (t < SCAN_BLOCKS) ? bsum[t] : 0;
    int x = v;
    for (int off = 1; off < 64; off <<= 1) {
        const int n = __shfl_up(x, off, 64);
        if ((t & 63) >= off) x += n;
    }
    __shared__ int wsum[4];
    if ((t & 63) == 63) wsum[t >> 6] = x;
    __syncthreads();
    const int w = t >> 6;
    int add = 0;
    for (int i = 0; i < w; ++i) add += wsum[i];
    if (t < SCAN_BLOCKS) boff[t] = x + add - v;   // exclusive
}

// ---------------------------------------------------------------------------
// 3c) scan pass 3: re-read cnt, in-block exclusive scan + boff[b], write
//     row_ptr[i] and rewrite cnt[i] in place as the scatter cursor.
//     (Each element is read and written only by its own thread -> safe.)
// ---------------------------------------------------------------------------
__global__ __launch_bounds__(256) void scan_write_kernel(int* __restrict__ cnt,
                                                         const int* __restrict__ boff,
                                                         int* __restrict__ row_ptr) {
    const int t = threadIdx.x;
    const int base = blockIdx.x * SCAN_CHUNK + t * 4;
    int v[4];
    int s = 0;
#pragma unroll
    for (int j = 0; j < 4; ++j) {
        const int i = base + j;
        v[j] = (i < N_NODES) ? cnt[i] : 0;
        s += v[j];
    }
    int x = s;
    for (int off = 1; off < 64; off <<= 1) {
        const int n = __shfl_up(x, off, 64);
        if ((t & 63) >= off) x += n;
    }
    __shared__ int wsum[4];
    if ((t & 63) == 63) wsum[t >> 6] = x;
    __syncthreads();
    const int w = t >> 6;
    int add = boff[blockIdx.x];
    for (int i = 0; i < w; ++i) add += wsum[i];
    int run = (x - s) + add;            // exclusive prefix of this thread's 1st elem
#pragma unroll
    for (int j = 0; j < 4; ++j) {
        const int i = base + j;
        if (i < N_NODES) {
            row_ptr[i] = run;
            cnt[i]     = run;           // becomes the scatter cursor
            run += v[j];
        }
    }
    if (blockIdx.x == 0 && t == 0) row_ptr[N_NODES] = NNZ_E;  // total is constant
}

// ---------------------------------------------------------------------------
// 4) scatter edges into CSR order (cursor = cnt)
// ---------------------------------------------------------------------------
__global__ void scatter_kernel(const int* __restrict__ rows, const int* __restrict__ cols,
                               const float* __restrict__ vals, int* __restrict__ cursor,
                               int* __restrict__ csr_col, float* __restrict__ csr_val) {
    const int stride = gridDim.x * blockDim.x;
    for (int e = blockIdx.x * blockDim.x + threadIdx.x; e < NNZ_E; e += stride) {
        int r = rows[e];
        int p = atomicAdd(&cursor[r], 1);
        csr_col[p] = cols[e];
        csr_val[p] = vals[e];
    }
}

// ---------------------------------------------------------------------------
// 5) SpMM pull, wide variant: one wave per row.
//    Lane layout: g = lane>>4 is the edge slot (4 concurrent edges),
//    d4 = (lane&15)*4 is the float4 dim base (16 lanes cover DIM=64).
//    2 edge-slots unrolled -> 8 edges in flight per iteration.
//    Epilogue: shfl_xor(16), shfl_xor(32) folds edge slots; lanes 0-15 store.
// ---------------------------------------------------------------------------
__global__ __launch_bounds__(256) void spmm_kernel(const int* __restrict__ row_ptr,
                            const int* __restrict__ csr_col, const float* __restrict__ csr_val,
                            const float* __restrict__ x_in, float* __restrict__ x_out) {
    const int lane = threadIdx.x & 63;
    const int row  = blockIdx.x * 4 + (threadIdx.x >> 6);
    if (row >= N_NODES) return;
    const int s  = row_ptr[row];
    const int e  = row_ptr[row + 1];
    const int g  = lane >> 4;         // edge slot 0..3
    const int d4 = (lane & 15) * 4;   // dim base

    float sx = 0.f, sy = 0.f, sz = 0.f, sw = 0.f;
    for (int i = s; i < e; i += 8) {
        const int idx0 = i + g;
        const int idx1 = i + g + 4;
        if (idx0 < e) {
            const int   c = csr_col[idx0];
            const float v = csr_val[idx0];
            const float4 xv = *reinterpret_cast<const float4*>(&x_in[(size_t)c * DIM + d4]);
            sx += v * xv.x; sy += v * xv.y; sz += v * xv.z; sw += v * xv.w;
        }
        if (idx1 < e) {
            const int   c = csr_col[idx1];
            const float v = csr_val[idx1];
            const float4 xv = *reinterpret_cast<const float4*>(&x_in[(size_t)c * DIM + d4]);
            sx += v * xv.x; sy += v * xv.y; sz += v * xv.z; sw += v * xv.w;
        }
    }
    // fold the 4 edge slots (lanes differing in bits 4,5 hold same dims)
    sx += __shfl_xor(sx, 16, 64); sy += __shfl_xor(sy, 16, 64);
    sz += __shfl_xor(sz, 16, 64); sw += __shfl_xor(sw, 16, 64);
    sx += __shfl_xor(sx, 32, 64); sy += __shfl_xor(sy, 32, 64);
    sz += __shfl_xor(sz, 32, 64); sw += __shfl_xor(sw, 32, 64);

    if (lane < 16) {
        float4 r; r.x = sx; r.y = sy; r.z = sz; r.w = sw;
        *reinterpret_cast<float4*>(&x_out[(size_t)row * DIM + d4]) = r;
    }
}

// ---------------------------------------------------------------------------
// 6) gather-accumulate queried rows into d_out: out += 0.25 * x[node]
//    (FIRST=true initializes out instead of adding)
// ---------------------------------------------------------------------------
template <bool FIRST>
__global__ void gacc_kernel(const float* __restrict__ x, const int* __restrict__ user_ids,
                            const int* __restrict__ item_ids, float* __restrict__ out) {
    const int tid = blockIdx.x * blockDim.x + threadIdx.x;
    if (tid >= 2 * NQ * DIM) return;
    const int i = tid >> 6;
    const int d = tid & 63;
    int node;
    if (i < NQ) node = user_ids[i];
    else        node = NUM_USERS + item_ids[i - NQ];
    float v = 0.25f * x[(size_t)node * DIM + d];
    if (FIRST) out[tid] = v;
    else       out[tid] += v;
}

// ---------------------------------------------------------------------------
extern "C" void kernel_launch(void* const* d_in, const int* in_sizes, int n_in,
                              void* d_out, int out_size, void* d_ws, size_t ws_size,
                              hipStream_t stream) {
    const float* user_emb  = (const float*)d_in[0];
    const float* item_emb  = (const float*)d_in[1];
    const float* edge_vals = (const float*)d_in[2];
    const int*   edge_rows = (const int*)d_in[3];
    const int*   edge_cols = (const int*)d_in[4];
    const int*   user_ids  = (const int*)d_in[5];
    const int*   item_ids  = (const int*)d_in[6];
    float* out = (float*)d_out;

    // workspace carve-up (256B aligned); total ~97.3 MB
    char* ws = (char*)d_ws;
    size_t off = 0;
    auto carve = [&](size_t bytes) {
        char* p = ws + off; off += (bytes + 255) & ~(size_t)255; return p;
    };
    float* x0      = (float*)carve((size_t)N_NODES * DIM * sizeof(float));   // 38.4 MB
    float* x1      = (float*)carve((size_t)N_NODES * DIM * sizeof(float));   // 38.4 MB
    int*   cnt     = (int*)  carve((size_t)N_NODES * sizeof(int));           // 0.6 MB
    int*   row_ptr = (int*)  carve((size_t)(N_NODES + 1) * sizeof(int));     // 0.6 MB
    int*   csr_col = (int*)  carve((size_t)NNZ_E * sizeof(int));             // 9.6 MB
    float* csr_val = (float*)carve((size_t)NNZ_E * sizeof(float));           // 9.6 MB
    int*   bsum    = (int*)  carve((size_t)SCAN_BLOCKS * sizeof(int));
    int*   boff    = (int*)  carve((size_t)SCAN_BLOCKS * sizeof(int));
    (void)in_sizes; (void)n_in; (void)out_size;

    // Defensive: never write past the provided workspace.
    if (ws_size < off) return;

    const int gth_grid = (2 * NQ * DIM + 255) / 256;

    // 1) init x0 (+ zero counters)
    hipLaunchKernelGGL(init_kernel, dim3(2048), dim3(256), 0, stream,
                       user_emb, item_emb, x0, cnt);
    // out = 0.25 * x0[queried]
    hipLaunchKernelGGL((gacc_kernel<true>), dim3(gth_grid), dim3(256), 0, stream,
                       x0, user_ids, item_ids, out);
    // 2) histogram
    hipLaunchKernelGGL(hist_kernel, dim3(2048), dim3(256), 0, stream, edge_rows, cnt);
    // 3) grid-wide exclusive scan (3 passes)
    hipLaunchKernelGGL(scan_reduce_kernel,  dim3(SCAN_BLOCKS), dim3(256), 0, stream, cnt, bsum);
    hipLaunchKernelGGL(scan_offsets_kernel, dim3(1),           dim3(256), 0, stream, bsum, boff);
    hipLaunchKernelGGL(scan_write_kernel,   dim3(SCAN_BLOCKS), dim3(256), 0, stream, cnt, boff, row_ptr);
    // 4) scatter into CSR
    hipLaunchKernelGGL(scatter_kernel, dim3(2048), dim3(256), 0, stream,
                       edge_rows, edge_cols, edge_vals, cnt, csr_col, csr_val);
    // 5) three SpMM hops (ping-pong x0/x1), each followed by gather-accumulate
    const int spmm_grid = (N_NODES + 3) / 4;   // 4 waves (rows) per 256-thread block
    float* xin = x0; float* xout = x1;
    for (int h = 0; h < 3; ++h) {
        hipLaunchKernelGGL(spmm_kernel, dim3(spmm_grid), dim3(256), 0, stream,
                           row_ptr, csr_col, csr_val, xin, xout);
        hipLaunchKernelGGL((gacc_kernel<false>), dim3(gth_grid), dim3(256), 0, stream,
                           xout, user_ids, item_ids, out);
        float* t = xin; xin = xout; xout = t;
    }
}

// Round 8
// 625.198 us; speedup vs baseline: 1.5628x; 1.0519x over previous
//
#include <hip/hip_runtime.h>

#define NUM_USERS 100000
#define NUM_ITEMS 50000
#define N_NODES   150000
#define DIM       64
#define NNZ_E     2400000
#define NQ        4096

#define SCAN_CHUNK  1024                                     // elements per block
#define SCAN_BLOCKS ((N_NODES + SCAN_CHUNK - 1) / SCAN_CHUNK) // 147
static_assert(SCAN_BLOCKS <= 256, "pass2 assumes <=256 block sums");

// ---------------------------------------------------------------------------
// 1) init: x0 = concat(user_emb, item_emb); zero the per-row counters
// ---------------------------------------------------------------------------
__global__ void init_kernel(const float* __restrict__ user_emb,
                            const float* __restrict__ item_emb,
                            float* __restrict__ x0, int* __restrict__ cnt) {
    const int total = N_NODES * DIM;
    const int stride = gridDim.x * blockDim.x;
    for (int i = blockIdx.x * blockDim.x + threadIdx.x; i < total; i += stride) {
        float v = (i < NUM_USERS * DIM) ? user_emb[i] : item_emb[i - NUM_USERS * DIM];
        x0[i] = v;
    }
    for (int i = blockIdx.x * blockDim.x + threadIdx.x; i < N_NODES; i += stride)
        cnt[i] = 0;
}

// ---------------------------------------------------------------------------
// 2) histogram of edge_rows
// ---------------------------------------------------------------------------
__global__ void hist_kernel(const int* __restrict__ rows, int* __restrict__ cnt) {
    const int stride = gridDim.x * blockDim.x;
    for (int e = blockIdx.x * blockDim.x + threadIdx.x; e < NNZ_E; e += stride)
        atomicAdd(&cnt[rows[e]], 1);
}

// ---------------------------------------------------------------------------
// 3a) scan pass 1: per-block reduction of cnt -> bsum[b]
// ---------------------------------------------------------------------------
__global__ __launch_bounds__(256) void scan_reduce_kernel(const int* __restrict__ cnt,
                                                          int* __restrict__ bsum) {
    const int t = threadIdx.x;
    const int base = blockIdx.x * SCAN_CHUNK + t * 4;
    int s = 0;
#pragma unroll
    for (int j = 0; j < 4; ++j) {
        const int i = base + j;
        if (i < N_NODES) s += cnt[i];
    }
    for (int off = 32; off; off >>= 1) s += __shfl_down(s, off, 64);
    __shared__ int ws[4];
    if ((t & 63) == 0) ws[t >> 6] = s;
    __syncthreads();
    if (t == 0) bsum[blockIdx.x] = ws[0] + ws[1] + ws[2] + ws[3];
}

// ---------------------------------------------------------------------------
// 3b) scan pass 2: single block, exclusive scan of the 147 block sums
// ---------------------------------------------------------------------------
__global__ __launch_bounds__(256) void scan_offsets_kernel(const int* __restrict__ bsum,
                                                           int* __restrict__ boff) {
    const int t = threadIdx.x;
    const int v = (t < SCAN_BLOCKS) ? bsum[t] : 0;
    int x = v;
    for (int off = 1; off < 64; off <<= 1) {
        const int n = __shfl_up(x, off, 64);
        if ((t & 63) >= off) x += n;
    }
    __shared__ int wsum[4];
    if ((t & 63) == 63) wsum[t >> 6] = x;
    __syncthreads();
    const int w = t >> 6;
    int add = 0;
    for (int i = 0; i < w; ++i) add += wsum[i];
    if (t < SCAN_BLOCKS) boff[t] = x + add - v;   // exclusive
}

// ---------------------------------------------------------------------------
// 3c) scan pass 3: in-block exclusive scan + boff[b] -> row_ptr, cursor
// ---------------------------------------------------------------------------
__global__ __launch_bounds__(256) void scan_write_kernel(int* __restrict__ cnt,
                                                         const int* __restrict__ boff,
                                                         int* __restrict__ row_ptr) {
    const int t = threadIdx.x;
    const int base = blockIdx.x * SCAN_CHUNK + t * 4;
    int v[4];
    int s = 0;
#pragma unroll
    for (int j = 0; j < 4; ++j) {
        const int i = base + j;
        v[j] = (i < N_NODES) ? cnt[i] : 0;
        s += v[j];
    }
    int x = s;
    for (int off = 1; off < 64; off <<= 1) {
        const int n = __shfl_up(x, off, 64);
        if ((t & 63) >= off) x += n;
    }
    __shared__ int wsum[4];
    if ((t & 63) == 63) wsum[t >> 6] = x;
    __syncthreads();
    const int w = t >> 6;
    int add = boff[blockIdx.x];
    for (int i = 0; i < w; ++i) add += wsum[i];
    int run = (x - s) + add;
#pragma unroll
    for (int j = 0; j < 4; ++j) {
        const int i = base + j;
        if (i < N_NODES) {
            row_ptr[i] = run;
            cnt[i]     = run;           // becomes the scatter cursor
            run += v[j];
        }
    }
    if (blockIdx.x == 0 && t == 0) row_ptr[N_NODES] = NNZ_E;
}

// ---------------------------------------------------------------------------
// 4) scatter edges into CSR order, INTERLEAVED (col, val_bits) int2 pairs:
//    one 8B random store per edge instead of two 4B stores to two arrays
//    -> halves distinct dirty-line touches (WRITE_SIZE was 12x amplified).
// ---------------------------------------------------------------------------
__global__ void scatter_kernel(const int* __restrict__ rows, const int* __restrict__ cols,
                               const float* __restrict__ vals, int* __restrict__ cursor,
                               int2* __restrict__ csr_pair) {
    const int stride = gridDim.x * blockDim.x;
    for (int e = blockIdx.x * blockDim.x + threadIdx.x; e < NNZ_E; e += stride) {
        int r = rows[e];
        int p = atomicAdd(&cursor[r], 1);
        csr_pair[p] = make_int2(cols[e], __float_as_int(vals[e]));
    }
}

// ---------------------------------------------------------------------------
// 5) SpMM pull: one wave per row. g = lane>>4 edge slot, d4 = (lane&15)*4
//    float4 dim base. 16 edges in flight per iteration (4 slots x 4 unroll),
//    branchless: dummy slots gather row 0 with weight 0.0 (adds exact 0).
// ---------------------------------------------------------------------------
__global__ __launch_bounds__(256) void spmm_kernel(const int* __restrict__ row_ptr,
                            const int2* __restrict__ csr_pair,
                            const float* __restrict__ x_in, float* __restrict__ x_out) {
    const int lane = threadIdx.x & 63;
    const int row  = blockIdx.x * 4 + (threadIdx.x >> 6);
    if (row >= N_NODES) return;
    const int s  = row_ptr[row];
    const int e  = row_ptr[row + 1];
    const int g  = lane >> 4;         // edge slot 0..3
    const int d4 = (lane & 15) * 4;   // dim base

    float sx = 0.f, sy = 0.f, sz = 0.f, sw = 0.f;
    for (int i = s; i < e; i += 16) {
        int   c[4];
        float v[4];
#pragma unroll
        for (int j = 0; j < 4; ++j) {
            const int idx = i + g + 4 * j;
            int2 ev = (idx < e) ? csr_pair[idx] : make_int2(0, 0);
            c[j] = ev.x;
            v[j] = __int_as_float(ev.y);   // 0 bits -> 0.0f for dummies
        }
#pragma unroll
        for (int j = 0; j < 4; ++j) {
            const float4 xv = *reinterpret_cast<const float4*>(
                &x_in[(size_t)c[j] * DIM + d4]);
            sx += v[j] * xv.x; sy += v[j] * xv.y;
            sz += v[j] * xv.z; sw += v[j] * xv.w;
        }
    }
    // fold the 4 edge slots (lanes differing in bits 4,5 hold same dims)
    sx += __shfl_xor(sx, 16, 64); sy += __shfl_xor(sy, 16, 64);
    sz += __shfl_xor(sz, 16, 64); sw += __shfl_xor(sw, 16, 64);
    sx += __shfl_xor(sx, 32, 64); sy += __shfl_xor(sy, 32, 64);
    sz += __shfl_xor(sz, 32, 64); sw += __shfl_xor(sw, 32, 64);

    if (lane < 16) {
        float4 r; r.x = sx; r.y = sy; r.z = sz; r.w = sw;
        *reinterpret_cast<float4*>(&x_out[(size_t)row * DIM + d4]) = r;
    }
}

// ---------------------------------------------------------------------------
// 6) gather-accumulate queried rows into d_out: out += 0.25 * x[node]
// ---------------------------------------------------------------------------
template <bool FIRST>
__global__ void gacc_kernel(const float* __restrict__ x, const int* __restrict__ user_ids,
                            const int* __restrict__ item_ids, float* __restrict__ out) {
    const int tid = blockIdx.x * blockDim.x + threadIdx.x;
    if (tid >= 2 * NQ * DIM) return;
    const int i = tid >> 6;
    const int d = tid & 63;
    int node;
    if (i < NQ) node = user_ids[i];
    else        node = NUM_USERS + item_ids[i - NQ];
    float v = 0.25f * x[(size_t)node * DIM + d];
    if (FIRST) out[tid] = v;
    else       out[tid] += v;
}

// ---------------------------------------------------------------------------
extern "C" void kernel_launch(void* const* d_in, const int* in_sizes, int n_in,
                              void* d_out, int out_size, void* d_ws, size_t ws_size,
                              hipStream_t stream) {
    const float* user_emb  = (const float*)d_in[0];
    const float* item_emb  = (const float*)d_in[1];
    const float* edge_vals = (const float*)d_in[2];
    const int*   edge_rows = (const int*)d_in[3];
    const int*   edge_cols = (const int*)d_in[4];
    const int*   user_ids  = (const int*)d_in[5];
    const int*   item_ids  = (const int*)d_in[6];
    float* out = (float*)d_out;

    // workspace carve-up (256B aligned); total ~97.3 MB
    char* ws = (char*)d_ws;
    size_t off = 0;
    auto carve = [&](size_t bytes) {
        char* p = ws + off; off += (bytes + 255) & ~(size_t)255; return p;
    };
    float* x0       = (float*)carve((size_t)N_NODES * DIM * sizeof(float));   // 38.4 MB
    float* x1       = (float*)carve((size_t)N_NODES * DIM * sizeof(float));   // 38.4 MB
    int*   cnt      = (int*)  carve((size_t)N_NODES * sizeof(int));           // 0.6 MB
    int*   row_ptr  = (int*)  carve((size_t)(N_NODES + 1) * sizeof(int));     // 0.6 MB
    int2*  csr_pair = (int2*) carve((size_t)NNZ_E * sizeof(int2));            // 19.2 MB
    int*   bsum     = (int*)  carve((size_t)SCAN_BLOCKS * sizeof(int));
    int*   boff     = (int*)  carve((size_t)SCAN_BLOCKS * sizeof(int));
    (void)in_sizes; (void)n_in; (void)out_size;

    // Defensive: never write past the provided workspace.
    if (ws_size < off) return;

    const int gth_grid = (2 * NQ * DIM + 255) / 256;

    // 1) init x0 (+ zero counters)
    hipLaunchKernelGGL(init_kernel, dim3(2048), dim3(256), 0, stream,
                       user_emb, item_emb, x0, cnt);
    // out = 0.25 * x0[queried]
    hipLaunchKernelGGL((gacc_kernel<true>), dim3(gth_grid), dim3(256), 0, stream,
                       x0, user_ids, item_ids, out);
    // 2) histogram
    hipLaunchKernelGGL(hist_kernel, dim3(2048), dim3(256), 0, stream, edge_rows, cnt);
    // 3) grid-wide exclusive scan (3 passes)
    hipLaunchKernelGGL(scan_reduce_kernel,  dim3(SCAN_BLOCKS), dim3(256), 0, stream, cnt, bsum);
    hipLaunchKernelGGL(scan_offsets_kernel, dim3(1),           dim3(256), 0, stream, bsum, boff);
    hipLaunchKernelGGL(scan_write_kernel,   dim3(SCAN_BLOCKS), dim3(256), 0, stream, cnt, boff, row_ptr);
    // 4) scatter into interleaved CSR
    hipLaunchKernelGGL(scatter_kernel, dim3(2048), dim3(256), 0, stream,
                       edge_rows, edge_cols, edge_vals, cnt, csr_pair);
    // 5) three SpMM hops (ping-pong x0/x1), each followed by gather-accumulate
    const int spmm_grid = (N_NODES + 3) / 4;   // 4 waves (rows) per 256-thread block
    float* xin = x0; float* xout = x1;
    for (int h = 0; h < 3; ++h) {
        hipLaunchKernelGGL(spmm_kernel, dim3(spmm_grid), dim3(256), 0, stream,
                           row_ptr, csr_pair, xin, xout);
        hipLaunchKernelGGL((gacc_kernel<false>), dim3(gth_grid), dim3(256), 0, stream,
                           xout, user_ids, item_ids, out);
        float* t = xin; xin = xout; xout = t;
    }
}

// Round 9
// 456.221 us; speedup vs baseline: 2.1417x; 1.3704x over previous
//
#include <hip/hip_runtime.h>

#define NUM_USERS 100000
#define NUM_ITEMS 50000
#define N_NODES   150000
#define DIM       64
#define NNZ_E     2400000
#define NQ        4096

#define NB         256                         // row-range buckets
#define RPB        587                         // rows per bucket (256*587=150272>=150000)
#define BCAP       10752                       // capacity: mean 9375 + ~14 sigma
#define EPT        16                          // edges per thread in binA
#define BINA_CHUNK (256 * EPT)                 // 4096 edges per block
#define BINA_BLOCKS ((NNZ_E + BINA_CHUNK - 1) / BINA_CHUNK)  // 586

// ---------------------------------------------------------------------------
// 1) init: x0 = concat(user_emb, item_emb); zero bucket cursors
// ---------------------------------------------------------------------------
__global__ void init_kernel(const float* __restrict__ user_emb,
                            const float* __restrict__ item_emb,
                            float* __restrict__ x0, int* __restrict__ bcur) {
    const int total = N_NODES * DIM;
    const int stride = gridDim.x * blockDim.x;
    const int tid = blockIdx.x * blockDim.x + threadIdx.x;
    for (int i = tid; i < total; i += stride) {
        float v = (i < NUM_USERS * DIM) ? user_emb[i] : item_emb[i - NUM_USERS * DIM];
        x0[i] = v;
    }
    if (tid < NB) bcur[tid] = 0;
}

// ---------------------------------------------------------------------------
// 2) pass A: bin edges into NB row-range buckets with LDS-staged run
//    reservation. Each block: LDS hist of its 4096 edges -> one global
//    atomicAdd per bucket -> writes ~128B contiguous runs (single-CU lines,
//    fully dirtied before eviction -> minimal writeback amplification).
//    Edge payload packed as ((row_local)<<18 | col, val_bits).
// ---------------------------------------------------------------------------
__global__ __launch_bounds__(256) void binA_kernel(const int* __restrict__ rows,
                                                   const int* __restrict__ cols,
                                                   const float* __restrict__ vals,
                                                   int* __restrict__ bcur,
                                                   int2* __restrict__ bucket) {
    __shared__ int hist[NB];
    __shared__ int runbase[NB];
    const int t = threadIdx.x;
    hist[t] = 0;                               // NB == blockDim.x == 256
    __syncthreads();

    const int base = blockIdx.x * BINA_CHUNK;
    unsigned pk[EPT];
    int bb[EPT];
#pragma unroll
    for (int j = 0; j < EPT; ++j) {
        const int idx = base + j * 256 + t;    // coalesced per j
        if (idx < NNZ_E) {
            const unsigned r = (unsigned)rows[idx];
            const unsigned c = (unsigned)cols[idx];
            const unsigned b = r / RPB;        // magic-mul constant division
            bb[j] = (int)b;
            pk[j] = ((r - b * RPB) << 18) | c; // rl(10b) | col(18b)
            atomicAdd(&hist[b], 1);
        } else bb[j] = -1;
    }
    __syncthreads();

    const int h = hist[t];
    runbase[t] = (h > 0) ? atomicAdd(&bcur[t], h) : 0;
    hist[t] = 0;                               // becomes local run cursor
    __syncthreads();

#pragma unroll
    for (int j = 0; j < EPT; ++j) {
        if (bb[j] >= 0) {
            const int idx  = base + j * 256 + t;
            const int ls   = atomicAdd(&hist[bb[j]], 1);
            const int slot = runbase[bb[j]] + ls;
            if (slot < BCAP)                   // statistically impossible overflow
                bucket[(size_t)bb[j] * BCAP + slot] =
                    make_int2((int)pk[j], __float_as_int(vals[idx]));
        }
    }
}

// ---------------------------------------------------------------------------
// 3) exclusive scan of the 256 bucket sizes -> bbase (CSR segment bases)
// ---------------------------------------------------------------------------
__global__ __launch_bounds__(256) void scan_bucket_kernel(const int* __restrict__ bcur,
                                                          int* __restrict__ bbase,
                                                          int* __restrict__ row_ptr) {
    const int t = threadIdx.x;
    const int v = bcur[t];
    int x = v;
    for (int off = 1; off < 64; off <<= 1) {
        const int n = __shfl_up(x, off, 64);
        if ((t & 63) >= off) x += n;
    }
    __shared__ int wsum[4];
    if ((t & 63) == 63) wsum[t >> 6] = x;
    __syncthreads();
    int add = 0;
    for (int i = 0; i < (t >> 6); ++i) add += wsum[i];
    bbase[t] = x + add - v;                    // exclusive
    if (t == 0) row_ptr[N_NODES] = NNZ_E;
}

// ---------------------------------------------------------------------------
// 4) pass B: one block per bucket. LDS row-hist -> LDS scan -> write row_ptr
//    and final dense CSR (col,val) into this block's exclusive contiguous
//    region [bbase[b], bbase[b]+size) -> single-CU write locality.
// ---------------------------------------------------------------------------
__global__ __launch_bounds__(256) void binB_kernel(const int* __restrict__ bcur,
                                                   const int* __restrict__ bbase,
                                                   const int2* __restrict__ bucket,
                                                   int2* __restrict__ csr_pair,
                                                   int* __restrict__ row_ptr) {
    __shared__ int hist[RPB];
    __shared__ int wsum[4];
    const int b = blockIdx.x;
    const int t = threadIdx.x;
    const int size = bcur[b];
    const int sz = size < BCAP ? size : BCAP;
    const size_t base_in = (size_t)b * BCAP;
    const int base_out = bbase[b];

    for (int i = t; i < RPB; i += 256) hist[i] = 0;
    __syncthreads();
    for (int i = t; i < sz; i += 256) {
        const unsigned rl = ((unsigned)bucket[base_in + i].x) >> 18;
        atomicAdd(&hist[rl], 1);
    }
    __syncthreads();

    // exclusive scan of hist[0..RPB): 3 elems/thread + wave/block scan
    const int e0 = t * 3;
    int v0 = (e0 + 0 < RPB) ? hist[e0 + 0] : 0;
    int v1 = (e0 + 1 < RPB) ? hist[e0 + 1] : 0;
    int v2 = (e0 + 2 < RPB) ? hist[e0 + 2] : 0;
    const int s = v0 + v1 + v2;
    int x = s;
    for (int off = 1; off < 64; off <<= 1) {
        const int n = __shfl_up(x, off, 64);
        if ((t & 63) >= off) x += n;
    }
    if ((t & 63) == 63) wsum[t >> 6] = x;
    __syncthreads();                           // all hist reads complete here
    int add = 0;
    for (int i = 0; i < (t >> 6); ++i) add += wsum[i];
    int run = (x - s) + add;                   // exclusive prefix for elem e0

    const int row0 = b * RPB;
    if (e0 + 0 < RPB) { hist[e0 + 0] = run; if (row0 + e0 + 0 < N_NODES) row_ptr[row0 + e0 + 0] = base_out + run; run += v0; }
    if (e0 + 1 < RPB) { hist[e0 + 1] = run; if (row0 + e0 + 1 < N_NODES) row_ptr[row0 + e0 + 1] = base_out + run; run += v1; }
    if (e0 + 2 < RPB) { hist[e0 + 2] = run; if (row0 + e0 + 2 < N_NODES) row_ptr[row0 + e0 + 2] = base_out + run; run += v2; }
    __syncthreads();

    for (int i = t; i < sz; i += 256) {
        const int2 ev = bucket[base_in + i];
        const unsigned rl = ((unsigned)ev.x) >> 18;
        const int slot = atomicAdd(&hist[rl], 1);
        csr_pair[base_out + slot] = make_int2(ev.x & 0x3FFFF, ev.y);
    }
}

// ---------------------------------------------------------------------------
// 5) SpMM pull: one wave per row. g = lane>>4 edge slot, d4 = (lane&15)*4
//    float4 dim base. 16 edges in flight per iteration, branchless dummies.
// ---------------------------------------------------------------------------
__global__ __launch_bounds__(256) void spmm_kernel(const int* __restrict__ row_ptr,
                            const int2* __restrict__ csr_pair,
                            const float* __restrict__ x_in, float* __restrict__ x_out) {
    const int lane = threadIdx.x & 63;
    const int row  = blockIdx.x * 4 + (threadIdx.x >> 6);
    if (row >= N_NODES) return;
    const int s  = row_ptr[row];
    const int e  = row_ptr[row + 1];
    const int g  = lane >> 4;         // edge slot 0..3
    const int d4 = (lane & 15) * 4;   // dim base

    float sx = 0.f, sy = 0.f, sz = 0.f, sw = 0.f;
    for (int i = s; i < e; i += 16) {
        int   c[4];
        float v[4];
#pragma unroll
        for (int j = 0; j < 4; ++j) {
            const int idx = i + g + 4 * j;
            int2 ev = (idx < e) ? csr_pair[idx] : make_int2(0, 0);
            c[j] = ev.x;
            v[j] = __int_as_float(ev.y);   // 0 bits -> 0.0f for dummies
        }
#pragma unroll
        for (int j = 0; j < 4; ++j) {
            const float4 xv = *reinterpret_cast<const float4*>(
                &x_in[(size_t)c[j] * DIM + d4]);
            sx += v[j] * xv.x; sy += v[j] * xv.y;
            sz += v[j] * xv.z; sw += v[j] * xv.w;
        }
    }
    sx += __shfl_xor(sx, 16, 64); sy += __shfl_xor(sy, 16, 64);
    sz += __shfl_xor(sz, 16, 64); sw += __shfl_xor(sw, 16, 64);
    sx += __shfl_xor(sx, 32, 64); sy += __shfl_xor(sy, 32, 64);
    sz += __shfl_xor(sz, 32, 64); sw += __shfl_xor(sw, 32, 64);

    if (lane < 16) {
        float4 r; r.x = sx; r.y = sy; r.z = sz; r.w = sw;
        *reinterpret_cast<float4*>(&x_out[(size_t)row * DIM + d4]) = r;
    }
}

// ---------------------------------------------------------------------------
// 6) gather-accumulate queried rows into d_out: out += 0.25 * x[node]
// ---------------------------------------------------------------------------
template <bool FIRST>
__global__ void gacc_kernel(const float* __restrict__ x, const int* __restrict__ user_ids,
                            const int* __restrict__ item_ids, float* __restrict__ out) {
    const int tid = blockIdx.x * blockDim.x + threadIdx.x;
    if (tid >= 2 * NQ * DIM) return;
    const int i = tid >> 6;
    const int d = tid & 63;
    int node;
    if (i < NQ) node = user_ids[i];
    else        node = NUM_USERS + item_ids[i - NQ];
    float v = 0.25f * x[(size_t)node * DIM + d];
    if (FIRST) out[tid] = v;
    else       out[tid] += v;
}

// ---------------------------------------------------------------------------
extern "C" void kernel_launch(void* const* d_in, const int* in_sizes, int n_in,
                              void* d_out, int out_size, void* d_ws, size_t ws_size,
                              hipStream_t stream) {
    const float* user_emb  = (const float*)d_in[0];
    const float* item_emb  = (const float*)d_in[1];
    const float* edge_vals = (const float*)d_in[2];
    const int*   edge_rows = (const int*)d_in[3];
    const int*   edge_cols = (const int*)d_in[4];
    const int*   user_ids  = (const int*)d_in[5];
    const int*   item_ids  = (const int*)d_in[6];
    float* out = (float*)d_out;

    // workspace carve-up (256B aligned); total ~96.7 MB
    char* ws = (char*)d_ws;
    size_t off = 0;
    auto carve = [&](size_t bytes) {
        char* p = ws + off; off += (bytes + 255) & ~(size_t)255; return p;
    };
    float* x0       = (float*)carve((size_t)N_NODES * DIM * sizeof(float));   // 38.4 MB
    float* x1       = (float*)carve((size_t)N_NODES * DIM * sizeof(float));   // 38.4 MB
    int2*  csr_pair = (int2*) carve((size_t)NNZ_E * sizeof(int2));            // 19.2 MB
    int*   row_ptr  = (int*)  carve((size_t)(N_NODES + 1) * sizeof(int));     // 0.6 MB
    int*   bcur     = (int*)  carve((size_t)NB * sizeof(int));
    int*   bbase    = (int*)  carve((size_t)NB * sizeof(int));
    // bucket staging (22.0 MB) aliased into x1: dead before hop-1 writes x1
    int2*  bucket   = (int2*)x1;
    static_assert((size_t)NB * BCAP * sizeof(int2) <= (size_t)N_NODES * DIM * sizeof(float),
                  "bucket staging must fit inside x1");
    (void)in_sizes; (void)n_in; (void)out_size;

    // Defensive: never write past the provided workspace.
    if (ws_size < off) return;

    const int gth_grid = (2 * NQ * DIM + 255) / 256;

    // 1) init x0 (+ zero bucket cursors)
    hipLaunchKernelGGL(init_kernel, dim3(2048), dim3(256), 0, stream,
                       user_emb, item_emb, x0, bcur);
    // out = 0.25 * x0[queried]
    hipLaunchKernelGGL((gacc_kernel<true>), dim3(gth_grid), dim3(256), 0, stream,
                       x0, user_ids, item_ids, out);
    // 2) pass A: bin edges into buckets (staged in x1's memory)
    hipLaunchKernelGGL(binA_kernel, dim3(BINA_BLOCKS), dim3(256), 0, stream,
                       edge_rows, edge_cols, edge_vals, bcur, bucket);
    // 3) scan bucket sizes -> CSR segment bases
    hipLaunchKernelGGL(scan_bucket_kernel, dim3(1), dim3(256), 0, stream,
                       bcur, bbase, row_ptr);
    // 4) pass B: per-bucket row sort -> row_ptr + dense CSR
    hipLaunchKernelGGL(binB_kernel, dim3(NB), dim3(256), 0, stream,
                       bcur, bbase, bucket, csr_pair, row_ptr);
    // 5) three SpMM hops (ping-pong x0/x1), each followed by gather-accumulate
    const int spmm_grid = (N_NODES + 3) / 4;   // 4 waves (rows) per 256-thread block
    float* xin = x0; float* xout = x1;
    for (int h = 0; h < 3; ++h) {
        hipLaunchKernelGGL(spmm_kernel, dim3(spmm_grid), dim3(256), 0, stream,
                           row_ptr, csr_pair, xin, xout);
        hipLaunchKernelGGL((gacc_kernel<false>), dim3(gth_grid), dim3(256), 0, stream,
                           xout, user_ids, item_ids, out);
        float* t = xin; xin = xout; xout = t;
    }
}